// Round 10
// baseline (199.793 us; speedup 1.0000x reference)
//
#include <hip/hip_runtime.h>
#include <math.h>

#define B_ 8
#define L_ 1024
#define E_ 512
#define H_ 8
#define D_ 64
#define QSZ (B_*H_*L_*D_)          // 4,194,304 elements
#define BLE ((size_t)B_*L_*E_)     // 4,194,304
#define TINYF 1.175494350822287508e-38f
#define SWK(r) ((((r) ^ ((r) >> 3))) & 7)   // full-entropy LDS chunk swizzle key

typedef unsigned short u16;
typedef __attribute__((ext_vector_type(8))) short bfrag;    // 8 bf16 (4 VGPRs)
typedef __attribute__((ext_vector_type(4))) float ffrag;    // 4 fp32 acc (16x16)
typedef __attribute__((ext_vector_type(16))) float ffrag16; // 16 fp32 acc (32x32)
typedef __attribute__((ext_vector_type(4))) short vshort4;

#if __has_builtin(__builtin_amdgcn_exp2f)
#define EXP2F(x) __builtin_amdgcn_exp2f(x)
#else
#define EXP2F(x) __expf((x) * 0.6931471805599453f)
#endif
#if __has_builtin(__builtin_amdgcn_rcpf)
#define RCPF(x) __builtin_amdgcn_rcpf(x)
#else
#define RCPF(x) (1.0f / (x))
#endif

__device__ __forceinline__ u16 f2b(float f) {
  unsigned u = __float_as_uint(f);
  u += 0x7fffu + ((u >> 16) & 1u);           // RNE
  return (u16)(u >> 16);
}
__device__ __forceinline__ unsigned pk2(float a, float b) {  // lo=rne(a), hi=rne(b)
  unsigned ua = __float_as_uint(a); ua += 0x7fffu + ((ua >> 16) & 1u);
  unsigned ub = __float_as_uint(b); ub += 0x7fffu + ((ub >> 16) & 1u);
  return (ua >> 16) | (ub & 0xffff0000u);
}
__device__ __forceinline__ float blo(unsigned u) { return __uint_as_float(u << 16); }
__device__ __forceinline__ float bhi(unsigned u) { return __uint_as_float(u & 0xffff0000u); }

__device__ __forceinline__ bfrag cvt8v(const float* __restrict__ src) {
  float4 a = *(const float4*)src;
  float4 b = *(const float4*)(src + 4);
  bfrag r;
  r[0]=(short)f2b(a.x); r[1]=(short)f2b(a.y); r[2]=(short)f2b(a.z); r[3]=(short)f2b(a.w);
  r[4]=(short)f2b(b.x); r[5]=(short)f2b(b.y); r[6]=(short)f2b(b.z); r[7]=(short)f2b(b.w);
  return r;
}

// async global->LDS, 16B per lane; lds base wave-uniform (HW adds lane*16)
__device__ __forceinline__ void gll16(const void* g, void* l) {
  __builtin_amdgcn_global_load_lds(
      (const __attribute__((address_space(1))) void*)g,
      (__attribute__((address_space(3))) void*)l, 16, 0, 0);
}

// ---- merged prep (fp32->bf16) + softmax(G) (writes actb bf16 and R[q][b]) ---
__global__ __launch_bounds__(256) void prep_softmax_k(
    const float* __restrict__ x, const float* __restrict__ Wq,
    const float* __restrict__ Wk, const float* __restrict__ Wv,
    const float* __restrict__ Wo, const float* __restrict__ G,
    const int* __restrict__ mask,
    u16* __restrict__ xb, u16* __restrict__ Wb, u16* __restrict__ actb,
    float* __restrict__ R) {
  const int bid = blockIdx.x, t = threadIdx.x;
  __shared__ float sred[8];
  __shared__ float rred[4][8];
  if (bid < 2048) {
    size_t c = (size_t)bid * 256 + t;
    *(bfrag*)&xb[c * 8] = cvt8v(x + c * 8);
    return;
  }
  if (bid < 2560) {
    const int c2 = bid - 2048;
    const float* src = (c2 < 128) ? Wq : (c2 < 256) ? Wk : (c2 < 384) ? Wv : Wo;
    const size_t base = (size_t)(c2 >> 7) * 262144;
    const size_t cc = (size_t)(c2 & 127) * 256 + t;
    *(bfrag*)&Wb[base + cc * 8] = cvt8v(src + cc * 8);
    return;
  }
  const int q = bid - 2560;
  const int w = t >> 6, lane = t & 63;
  float4 g4 = ((const float4*)(G + (size_t)q * 1024))[t];
  float m = fmaxf(fmaxf(g4.x, g4.y), fmaxf(g4.z, g4.w));
#pragma unroll
  for (int off = 32; off > 0; off >>= 1) m = fmaxf(m, __shfl_down(m, off));
  if (lane == 0) sred[w] = m;
  __syncthreads();
  m = fmaxf(fmaxf(sred[0], sred[1]), fmaxf(sred[2], sred[3]));
  float e0 = __expf(g4.x - m), e1 = __expf(g4.y - m);
  float e2 = __expf(g4.z - m), e3 = __expf(g4.w - m);
  float s = e0 + e1 + e2 + e3;
#pragma unroll
  for (int off = 32; off > 0; off >>= 1) s += __shfl_down(s, off);
  if (lane == 0) sred[4 + w] = s;
  __syncthreads();
  const float inv = 1.0f / (sred[4] + sred[5] + sred[6] + sred[7]);
  const unsigned p0 = pk2(e0 * inv, e1 * inv);
  const unsigned p1 = pk2(e2 * inv, e3 * inv);
  *(uint2*)&actb[(size_t)q * 1024 + t * 4] = make_uint2(p0, p1);
  const float r0 = blo(p0), r1 = bhi(p0);
  const float r2 = blo(p1), r3 = bhi(p1);
  float rd[8];
#pragma unroll
  for (int b = 0; b < 8; ++b) {
    const int* mkp = mask + b * 1024 + t * 4;
    rd[b] = (mkp[0] ? r0 : 0.f) + (mkp[1] ? r1 : 0.f) +
            (mkp[2] ? r2 : 0.f) + (mkp[3] ? r3 : 0.f);
#pragma unroll
    for (int off = 32; off > 0; off >>= 1) rd[b] += __shfl_down(rd[b], off);
  }
  if (lane == 0)
#pragma unroll
    for (int b = 0; b < 8; ++b) rred[w][b] = rd[b];
  __syncthreads();
  if (t < 8) R[q * 8 + t] = rred[0][t] + rred[1][t] + rred[2][t] + rred[3][t];
}

// ---- QKV projection GEMM; block (0,0) also zeroes denom + reduces gsums -----
__global__ __launch_bounds__(256) void proj_k(
    const u16* __restrict__ xb, const u16* __restrict__ Wb,
    const int* __restrict__ mask, const float* __restrict__ R,
    float* __restrict__ sums,
    u16* __restrict__ Qb, u16* __restrict__ Kb, u16* __restrict__ Vtb) {
  const int m0 = blockIdx.x * 128;
  const int n0 = blockIdx.y * 64;
  __shared__ u16 As[128 * 64];
  __shared__ u16 Bs[64 * 64];
  __shared__ float rr[4][8];
  const int t = threadIdx.x, w = t >> 6, lane = t & 63;
  const int l15 = lane & 15, quad = lane >> 4;
  const int x7 = l15 & 7;

  if (blockIdx.x == 0 && blockIdx.y == 0) {   // gsums + denom-zero (hidden)
    float a8[8] = {0,0,0,0,0,0,0,0};
    for (int q = t; q < 1024; q += 256)
#pragma unroll
      for (int b = 0; b < 8; ++b)
        if (mask[b * 1024 + q]) a8[b] += R[q * 8 + b];
#pragma unroll
    for (int b = 0; b < 8; ++b) {
#pragma unroll
      for (int off = 32; off > 0; off >>= 1) a8[b] += __shfl_down(a8[b], off);
    }
    if (lane == 0)
#pragma unroll
      for (int b = 0; b < 8; ++b) rr[w][b] = a8[b];
    __syncthreads();
    if (t < 8) {
      sums[t] = 0.0f;
      sums[8 + t] = rr[0][t] + rr[1][t] + rr[2][t] + rr[3][t];
    }
  }

  const ffrag fz = {0.f, 0.f, 0.f, 0.f};
  ffrag acc[2][4];
#pragma unroll
  for (int am = 0; am < 2; ++am)
#pragma unroll
    for (int bn = 0; bn < 4; ++bn) acc[am][bn] = fz;

  for (int kk = 0; kk < 512; kk += 64) {
    __syncthreads();
#pragma unroll
    for (int j = 0; j < 4; ++j) {
      const int c = w * 256 + j * 64 + lane;
      const int row = c >> 3, ck = (c & 7) ^ (row & 7);
      gll16(xb + (size_t)(m0 + row) * 512 + kk + ck * 8,
            &As[(size_t)(w * 256 + j * 64) * 8]);
    }
#pragma unroll
    for (int j = 0; j < 2; ++j) {
      const int c = w * 128 + j * 64 + lane;
      const int row = c >> 3, ck = (c & 7) ^ (row & 7);
      gll16(Wb + (size_t)(n0 + row) * 512 + kk + ck * 8,
            &Bs[(size_t)(w * 128 + j * 64) * 8]);
    }
    __syncthreads();
#pragma unroll
    for (int s = 0; s < 2; ++s) {
      const int co = ((quad + 4 * s) ^ x7) << 3;
      bfrag a0 = *(const bfrag*)&As[(w * 32 + l15) * 64 + co];
      bfrag a1 = *(const bfrag*)&As[(w * 32 + 16 + l15) * 64 + co];
#pragma unroll
      for (int bn = 0; bn < 4; ++bn) {
        bfrag bb = *(const bfrag*)&Bs[(bn * 16 + l15) * 64 + co];
        acc[0][bn] = __builtin_amdgcn_mfma_f32_16x16x32_bf16(a0, bb, acc[0][bn], 0, 0, 0);
        acc[1][bn] = __builtin_amdgcn_mfma_f32_16x16x32_bf16(a1, bb, acc[1][bn], 0, 0, 0);
      }
    }
  }
  const int z = n0 >> 9;
  const int c0 = n0 & 511;
#pragma unroll
  for (int am = 0; am < 2; ++am) {
    const int mbase = m0 + w * 32 + am * 16 + quad * 4;
    const int b = mbase >> 10, l0 = mbase & 1023;
#pragma unroll
    for (int bn = 0; bn < 4; ++bn) {
      const int nc = c0 + bn * 16 + l15;
      const int h = nc >> 6, d = nc & 63;
      if (z == 0) {
        u16* dst = Qb + ((size_t)(b * 8 + h) * 1024 + l0) * 64 + d;
#pragma unroll
        for (int r = 0; r < 4; ++r) dst[(size_t)r * 64] = f2b(acc[am][bn][r]);
      } else if (z == 1) {
        u16* dst = Kb + ((size_t)(b * 8 + h) * 1024 + l0) * 64 + d;
#pragma unroll
        for (int r = 0; r < 4; ++r) dst[(size_t)r * 64] = f2b(acc[am][bn][r]);
      } else {
        vshort4 vs;
#pragma unroll
        for (int r = 0; r < 4; ++r)
          vs[r] = (short)(mask[b * 1024 + l0 + r] ? f2b(acc[am][bn][r]) : (u16)0);
        *(vshort4*)(Vtb + ((size_t)(b * 8 + h) * 64 + d) * 1024 + l0) = vs;
      }
    }
  }
}

// ---- fused tanh-attention + global-mix GEMM, 32x32 MFMA, 1 barrier/kt ------
// Wave (qb2=w>>1, kb=w&1) owns a q32 x k32 quadrant end-to-end: S^T via MFMA,
// nonlinearity, in-register C->A shfl transform (no Es LDS), then partial-k
// PV into accE/accG (q32 x d64). K/V/act double-buffered -> single barrier
// per kt. kb-halves merged via LDS reduce at epilogue; denom atomics compose.
__global__ __launch_bounds__(256) void attn_k(
    const u16* __restrict__ Qb, const u16* __restrict__ Kb,
    const u16* __restrict__ Vtb, const u16* __restrict__ actb,
    const int* __restrict__ mask,
    u16* __restrict__ AEb, u16* __restrict__ AGb, float* __restrict__ denom) {
  const int qt = blockIdx.x;
  const int bh = blockIdx.y;
  const int b = bh >> 3, h = bh & 7;
  __shared__ __align__(16) u16 Ks[2][64 * 64];    // 16 KB [k][d]
  __shared__ __align__(16) u16 Vs[2][64 * 64];    // 16 KB [d][k]
  __shared__ __align__(16) u16 Acts[2][64 * 64];  // 16 KB [q][k]
  __shared__ __align__(16) u16 Ms[1024];          //  2 KB bf16 mask
  __shared__ float red8[8];
  const int t = threadIdx.x, w = t >> 6, lane = t & 63;
  const int l31 = lane & 31, hi = lane >> 5;
  const int qb2 = w >> 1, kb = w & 1;   // wave quadrant: q-block, k-half

  const u16* Kg = Kb + (size_t)bh * 65536;
  const u16* Vg = Vtb + (size_t)bh * 65536;
  const u16* Ag = actb + (size_t)(qt * 64) * 1024;

  // Q B-frags in registers (n = q = l31; K-dim = d)
  const u16* Qrow = Qb + ((size_t)bh * 1024 + qt * 64 + qb2 * 32 + l31) * 64;
  bfrag qf[4];
#pragma unroll
  for (int ko = 0; ko < 4; ++ko) qf[ko] = *(const bfrag*)(Qrow + ko * 16 + hi * 8);

  // mask tile (bf16 1.0/0.0) for denominator B-frags
  {
    int4 mi = *(const int4*)(mask + b * 1024 + t * 4);
    vshort4 mv;
    mv[0] = mi.x ? (short)0x3F80 : (short)0; mv[1] = mi.y ? (short)0x3F80 : (short)0;
    mv[2] = mi.z ? (short)0x3F80 : (short)0; mv[3] = mi.w ? (short)0x3F80 : (short)0;
    *(vshort4*)&Ms[t * 4] = mv;
  }

  auto stageAll = [&](int p, int kt) {
#pragma unroll
    for (int j = 0; j < 2; ++j) {
      const int c = w * 128 + j * 64 + lane;
      const int row = c >> 3, ck = (c & 7) ^ SWK(row);
      gll16(Kg + (size_t)(kt * 64 + row) * 64 + ck * 8,
            &Ks[p][(size_t)(w * 128 + j * 64) * 8]);
      gll16(Vg + (size_t)row * 1024 + kt * 64 + ck * 8,
            &Vs[p][(size_t)(w * 128 + j * 64) * 8]);
      gll16(Ag + (size_t)row * 1024 + kt * 64 + ck * 8,
            &Acts[p][(size_t)(w * 128 + j * 64) * 8]);
    }
  };

  stageAll(0, 0);
  __syncthreads();

  ffrag16 accE[2], accG[2], dacc;
#pragma unroll
  for (int i = 0; i < 16; ++i) {
    accE[0][i] = 0.f; accE[1][i] = 0.f; accG[0][i] = 0.f; accG[1][i] = 0.f;
    dacc[i] = 0.f;
  }

  const int krow = kb * 32 + l31;
  const int kk7 = SWK(krow);
  const int arow = qb2 * 32 + l31;
  const int ak7 = SWK(arow);

  for (int kt = 0; kt < 16; ++kt) {
    const int p = kt & 1;
    if (kt < 15) stageAll(1 - p, kt + 1);   // overlaps full kt compute

    // ---- S-phase: S^T quadrant (m = wave's k32, n = its q32) ----
    ffrag16 st;
#pragma unroll
    for (int i = 0; i < 16; ++i) st[i] = 0.f;
#pragma unroll
    for (int ko = 0; ko < 4; ++ko) {
      bfrag ak = *(const bfrag*)&Ks[p][krow * 64 + (((ko * 2 + hi) ^ kk7) << 3)];
      st = __builtin_amdgcn_mfma_f32_32x32x16_bf16(ak, qf[ko], st, 0, 0, 0);
    }

    // ---- nonlinearity + in-register C->A transform (verified in R7) ----
    // C-layout: lane q=l31, k_local=(r&3)+8*(r>>2)+4*hi; pairs (2j,2j+1) are
    // consecutive k; partner lane (l^32) holds complementary k-sets.
    unsigned P[8];
#pragma unroll
    for (int j = 0; j < 8; ++j) {
      const float t0 = EXP2F(st[2 * j] * 0.360673760222f);
      const float e0 = EXP2F(RCPF(t0 + 1.0f) * -2.88539008178f);
      const float t1 = EXP2F(st[2 * j + 1] * 0.360673760222f);
      const float e1 = EXP2F(RCPF(t1 + 1.0f) * -2.88539008178f);
      P[j] = pk2(e0, e1);
    }
    bfrag ef[2];
#pragma unroll
    for (int g = 0; g < 2; ++g) {
      const unsigned q0 = P[4 * g + 0], q1 = P[4 * g + 1];
      const unsigned q2 = P[4 * g + 2], q3 = P[4 * g + 3];
      const unsigned r0 = (unsigned)__shfl_xor((int)q0, 32);
      const unsigned r1 = (unsigned)__shfl_xor((int)q1, 32);
      const unsigned r2 = (unsigned)__shfl_xor((int)q2, 32);
      const unsigned r3 = (unsigned)__shfl_xor((int)q3, 32);
      union { uint4 u; bfrag f; } cv;
      cv.u.x = hi ? r2 : q0;
      cv.u.y = hi ? r3 : q1;
      cv.u.z = hi ? q2 : r0;
      cv.u.w = hi ? q3 : r1;
      ef[g] = cv.f;
    }

    // ---- denominator partial: dacc += E @ mask(k-half) ----
#pragma unroll
    for (int ko = 0; ko < 2; ++ko) {
      bfrag bm = *(const bfrag*)&Ms[kt * 64 + kb * 32 + ko * 16 + hi * 8];
      dacc = __builtin_amdgcn_mfma_f32_32x32x16_bf16(ef[ko], bm, dacc, 0, 0, 0);
    }

    // ---- PV partial-k: accE += E@V, accG += act@V over wave's k32 ----
#pragma unroll
    for (int ko = 0; ko < 2; ++ko) {
      const int co = kb * 4 + ko * 2 + hi;
      bfrag aa = *(const bfrag*)&Acts[p][arow * 64 + ((co ^ ak7) << 3)];
#pragma unroll
      for (int db = 0; db < 2; ++db) {
        const int vrow = db * 32 + l31;
        bfrag bv = *(const bfrag*)&Vs[p][vrow * 64 + ((co ^ SWK(vrow)) << 3)];
        accE[db] = __builtin_amdgcn_mfma_f32_32x32x16_bf16(ef[ko], bv, accE[db], 0, 0, 0);
        accG[db] = __builtin_amdgcn_mfma_f32_32x32x16_bf16(aa, bv, accG[db], 0, 0, 0);
      }
    }
    __syncthreads();   // single drain: buf[p] reads done, buf[1-p] GLL complete
  }

  // ---- epilogue: merge kb halves via LDS, store bf16; denom reduce ----
  float* redE = (float*)Ks;   // 16 KB scratch
  float* redG = (float*)Vs;   // 16 KB scratch
  if (kb == 1) {
#pragma unroll
    for (int db = 0; db < 2; ++db)
#pragma unroll
      for (int r = 0; r < 16; ++r) {
        redE[(qb2 * 2 + db) * 1024 + r * 64 + lane] = accE[db][r];
        redG[(qb2 * 2 + db) * 1024 + r * 64 + lane] = accG[db][r];
      }
  }
  float dsumv = 0.0f;
  if (l31 == 0) {
    const int qb0 = b * 1024 + qt * 64 + qb2 * 32 + 4 * hi;
#pragma unroll
    for (int r = 0; r < 16; ++r) {
      const int q = qb0 + (r & 3) + 8 * (r >> 2);
      dsumv += mask[q] ? dacc[r] : 0.0f;
    }
    red8[w * 2 + hi] = dsumv;
  }
  __syncthreads();
  if (kb == 0) {
    const size_t obase = ((size_t)(b * 1024 + qt * 64 + qb2 * 32)) * 512
                         + h * 64 + l31;
#pragma unroll
    for (int db = 0; db < 2; ++db)
#pragma unroll
      for (int r = 0; r < 16; ++r) {
        const float vE = accE[db][r] + redE[(qb2 * 2 + db) * 1024 + r * 64 + lane];
        const float vG = accG[db][r] + redG[(qb2 * 2 + db) * 1024 + r * 64 + lane];
        const int qloc = (r & 3) + 8 * (r >> 2) + 4 * hi;
        AEb[obase + db * 32 + (size_t)qloc * 512] = f2b(vE);
        AGb[obase + db * 32 + (size_t)qloc * 512] = f2b(vG);
      }
  }
  if (t == 0)
    atomicAdd(denom + b, red8[0] + red8[1] + red8[2] + red8[3] +
                         red8[4] + red8[5] + red8[6] + red8[7]);
}

// ---- out = (mq*(c1*AEb + c2*AGb)) @ Wo^T ------------------------------------
__global__ __launch_bounds__(256) void o_proj_k(
    const u16* __restrict__ AEb, const u16* __restrict__ AGb,
    const int* __restrict__ mask, const float* __restrict__ sums,
    const u16* __restrict__ Wb, float* __restrict__ out) {
  const int m0 = blockIdx.x * 128;
  const int n0 = blockIdx.y * 64;
  const int b = m0 >> 10;
  const float c1 = 0.5f / fmaxf(sums[b], TINYF);
  const float c2 = 0.5f / fmaxf(sums[8 + b], TINYF);
  __shared__ __align__(16) u16 As[128 * 64];
  __shared__ __align__(16) u16 Bs[64 * 64];
  const int t = threadIdx.x, w = t >> 6, lane = t & 63;
  const int l15 = lane & 15, quad = lane >> 4;
  const int x7 = l15 & 7;
  int rowi[4]; float c1r[4], c2r[4];
#pragma unroll
  for (int i = 0; i < 4; ++i) {
    const int c = t + i * 256;
    rowi[i] = c >> 3;
    const int mq = mask[b * 1024 + ((m0 + rowi[i]) & 1023)];
    c1r[i] = mq ? c1 : 0.0f;
    c2r[i] = mq ? c2 : 0.0f;
  }
  const ffrag fz = {0.f, 0.f, 0.f, 0.f};
  ffrag acc[2][4];
#pragma unroll
  for (int am = 0; am < 2; ++am)
#pragma unroll
    for (int bn = 0; bn < 4; ++bn) acc[am][bn] = fz;

  for (int kk = 0; kk < 512; kk += 64) {
    __syncthreads();
#pragma unroll
    for (int i = 0; i < 4; ++i) {
      const int c = t + i * 256;
      const int row = rowi[i], ck = c & 7;
      const size_t gofs = (size_t)(m0 + row) * 512 + kk + ck * 8;
      uint4 ua = *(const uint4*)(AEb + gofs);
      uint4 ug = *(const uint4*)(AGb + gofs);
      const float a1 = c1r[i], a2 = c2r[i];
      uint4 res;
      res.x = pk2(a1 * blo(ua.x) + a2 * blo(ug.x), a1 * bhi(ua.x) + a2 * bhi(ug.x));
      res.y = pk2(a1 * blo(ua.y) + a2 * blo(ug.y), a1 * bhi(ua.y) + a2 * bhi(ug.y));
      res.z = pk2(a1 * blo(ua.z) + a2 * blo(ug.z), a1 * bhi(ua.z) + a2 * bhi(ug.z));
      res.w = pk2(a1 * blo(ua.w) + a2 * blo(ug.w), a1 * bhi(ua.w) + a2 * bhi(ug.w));
      *(uint4*)&As[row * 64 + ((ck ^ (row & 7)) << 3)] = res;
    }
#pragma unroll
    for (int j = 0; j < 2; ++j) {
      const int c = w * 128 + j * 64 + lane;
      const int row = c >> 3, ck = (c & 7) ^ (row & 7);
      gll16(Wb + (size_t)(1536 + n0 + row) * 512 + kk + ck * 8,
            &Bs[(size_t)(w * 128 + j * 64) * 8]);
    }
    __syncthreads();
#pragma unroll
    for (int s = 0; s < 2; ++s) {
      const int co = ((quad + 4 * s) ^ x7) << 3;
      bfrag a0 = *(const bfrag*)&As[(w * 32 + l15) * 64 + co];
      bfrag a1 = *(const bfrag*)&As[(w * 32 + 16 + l15) * 64 + co];
#pragma unroll
      for (int bn = 0; bn < 4; ++bn) {
        bfrag bb = *(const bfrag*)&Bs[(bn * 16 + l15) * 64 + co];
        acc[0][bn] = __builtin_amdgcn_mfma_f32_16x16x32_bf16(a0, bb, acc[0][bn], 0, 0, 0);
        acc[1][bn] = __builtin_amdgcn_mfma_f32_16x16x32_bf16(a1, bb, acc[1][bn], 0, 0, 0);
      }
    }
  }
#pragma unroll
  for (int am = 0; am < 2; ++am) {
    const int mbase = m0 + w * 32 + am * 16 + quad * 4;
#pragma unroll
    for (int bn = 0; bn < 4; ++bn) {
      const int n = n0 + bn * 16 + l15;
#pragma unroll
      for (int r = 0; r < 4; ++r)
        out[(size_t)(mbase + r) * 512 + n] = acc[am][bn][r];
    }
  }
}

extern "C" void kernel_launch(void* const* d_in, const int* in_sizes, int n_in,
                              void* d_out, int out_size, void* d_ws, size_t ws_size,
                              hipStream_t stream) {
  const float* x  = (const float*)d_in[0];
  const int* mask = (const int*)d_in[1];
  const float* Wq = (const float*)d_in[2];
  const float* Wk = (const float*)d_in[3];
  const float* Wv = (const float*)d_in[4];
  const float* Wo = (const float*)d_in[5];
  const float* G  = (const float*)d_in[6];
  float* out = (float*)d_out;

  u16* xb   = (u16*)d_ws;                    // 8192*512
  u16* Wb   = xb + (size_t)8192 * 512;       // 2048*512
  u16* Qb   = Wb + (size_t)2048 * 512;       // QSZ
  u16* Kb   = Qb + QSZ;
  u16* Vtb  = Kb + QSZ;
  u16* actb = Vtb + QSZ;                     // 1024*1024
  u16* AEb  = actb + (size_t)1024 * 1024;    // BLE
  u16* AGb  = AEb + BLE;                     // BLE
  float* R  = (float*)(AGb + BLE);           // 1024*8
  float* SUMS = R + 8192;                    // denom[8], gsums[8]

  prep_softmax_k<<<3584, 256, 0, stream>>>(x, Wq, Wk, Wv, Wo, G, mask, xb, Wb, actb, R);
  proj_k<<<dim3(64, 24), 256, 0, stream>>>(xb, Wb, mask, R, SUMS, Qb, Kb, Vtb);
  attn_k<<<dim3(16, 64), 256, 0, stream>>>(Qb, Kb, Vtb, actb, mask, AEb, AGb, SUMS);
  o_proj_k<<<dim3(64, 8), 256, 0, stream>>>(AEb, AGb, mask, SUMS, Wb, out);
}

// Round 11
// 186.385 us; speedup vs baseline: 1.0719x; 1.0719x over previous
//
#include <hip/hip_runtime.h>
#include <math.h>

#define B_ 8
#define L_ 1024
#define E_ 512
#define H_ 8
#define D_ 64
#define QSZ (B_*H_*L_*D_)          // 4,194,304 elements
#define BLE ((size_t)B_*L_*E_)     // 4,194,304
#define TINYF 1.175494350822287508e-38f
#define SWK(r) ((((r) ^ ((r) >> 3))) & 7)   // full-entropy LDS chunk swizzle key

typedef unsigned short u16;
typedef __attribute__((ext_vector_type(8))) short bfrag;    // 8 bf16 (4 VGPRs)
typedef __attribute__((ext_vector_type(4))) float ffrag;    // 4 fp32 acc (16x16)
typedef __attribute__((ext_vector_type(16))) float ffrag16; // 16 fp32 acc (32x32)
typedef __attribute__((ext_vector_type(4))) short vshort4;

#if __has_builtin(__builtin_amdgcn_exp2f)
#define EXP2F(x) __builtin_amdgcn_exp2f(x)
#else
#define EXP2F(x) __expf((x) * 0.6931471805599453f)
#endif
#if __has_builtin(__builtin_amdgcn_rcpf)
#define RCPF(x) __builtin_amdgcn_rcpf(x)
#else
#define RCPF(x) (1.0f / (x))
#endif

__device__ __forceinline__ u16 f2b(float f) {
  unsigned u = __float_as_uint(f);
  u += 0x7fffu + ((u >> 16) & 1u);           // RNE
  return (u16)(u >> 16);
}
__device__ __forceinline__ unsigned pk2(float a, float b) {  // lo=rne(a), hi=rne(b)
  unsigned ua = __float_as_uint(a); ua += 0x7fffu + ((ua >> 16) & 1u);
  unsigned ub = __float_as_uint(b); ub += 0x7fffu + ((ub >> 16) & 1u);
  return (ua >> 16) | (ub & 0xffff0000u);
}
__device__ __forceinline__ float blo(unsigned u) { return __uint_as_float(u << 16); }
__device__ __forceinline__ float bhi(unsigned u) { return __uint_as_float(u & 0xffff0000u); }

__device__ __forceinline__ bfrag cvt8v(const float* __restrict__ src) {
  float4 a = *(const float4*)src;
  float4 b = *(const float4*)(src + 4);
  bfrag r;
  r[0]=(short)f2b(a.x); r[1]=(short)f2b(a.y); r[2]=(short)f2b(a.z); r[3]=(short)f2b(a.w);
  r[4]=(short)f2b(b.x); r[5]=(short)f2b(b.y); r[6]=(short)f2b(b.z); r[7]=(short)f2b(b.w);
  return r;
}

// async global->LDS, 16B per lane; lds base wave-uniform (HW adds lane*16)
__device__ __forceinline__ void gll16(const void* g, void* l) {
  __builtin_amdgcn_global_load_lds(
      (const __attribute__((address_space(1))) void*)g,
      (__attribute__((address_space(3))) void*)l, 16, 0, 0);
}

// ---- merged prep (fp32->bf16) + softmax(G) (writes actb bf16 and R[q][b]) ---
__global__ __launch_bounds__(256) void prep_softmax_k(
    const float* __restrict__ x, const float* __restrict__ Wq,
    const float* __restrict__ Wk, const float* __restrict__ Wv,
    const float* __restrict__ Wo, const float* __restrict__ G,
    const int* __restrict__ mask,
    u16* __restrict__ xb, u16* __restrict__ Wb, u16* __restrict__ actb,
    float* __restrict__ R) {
  const int bid = blockIdx.x, t = threadIdx.x;
  __shared__ float sred[8];
  __shared__ float rred[4][8];
  if (bid < 2048) {
    size_t c = (size_t)bid * 256 + t;
    *(bfrag*)&xb[c * 8] = cvt8v(x + c * 8);
    return;
  }
  if (bid < 2560) {
    const int c2 = bid - 2048;
    const float* src = (c2 < 128) ? Wq : (c2 < 256) ? Wk : (c2 < 384) ? Wv : Wo;
    const size_t base = (size_t)(c2 >> 7) * 262144;
    const size_t cc = (size_t)(c2 & 127) * 256 + t;
    *(bfrag*)&Wb[base + cc * 8] = cvt8v(src + cc * 8);
    return;
  }
  const int q = bid - 2560;
  const int w = t >> 6, lane = t & 63;
  float4 g4 = ((const float4*)(G + (size_t)q * 1024))[t];
  float m = fmaxf(fmaxf(g4.x, g4.y), fmaxf(g4.z, g4.w));
#pragma unroll
  for (int off = 32; off > 0; off >>= 1) m = fmaxf(m, __shfl_down(m, off));
  if (lane == 0) sred[w] = m;
  __syncthreads();
  m = fmaxf(fmaxf(sred[0], sred[1]), fmaxf(sred[2], sred[3]));
  float e0 = __expf(g4.x - m), e1 = __expf(g4.y - m);
  float e2 = __expf(g4.z - m), e3 = __expf(g4.w - m);
  float s = e0 + e1 + e2 + e3;
#pragma unroll
  for (int off = 32; off > 0; off >>= 1) s += __shfl_down(s, off);
  if (lane == 0) sred[4 + w] = s;
  __syncthreads();
  const float inv = 1.0f / (sred[4] + sred[5] + sred[6] + sred[7]);
  const unsigned p0 = pk2(e0 * inv, e1 * inv);
  const unsigned p1 = pk2(e2 * inv, e3 * inv);
  *(uint2*)&actb[(size_t)q * 1024 + t * 4] = make_uint2(p0, p1);
  const float r0 = blo(p0), r1 = bhi(p0);
  const float r2 = blo(p1), r3 = bhi(p1);
  float rd[8];
#pragma unroll
  for (int b = 0; b < 8; ++b) {
    const int* mkp = mask + b * 1024 + t * 4;
    rd[b] = (mkp[0] ? r0 : 0.f) + (mkp[1] ? r1 : 0.f) +
            (mkp[2] ? r2 : 0.f) + (mkp[3] ? r3 : 0.f);
#pragma unroll
    for (int off = 32; off > 0; off >>= 1) rd[b] += __shfl_down(rd[b], off);
  }
  if (lane == 0)
#pragma unroll
    for (int b = 0; b < 8; ++b) rred[w][b] = rd[b];
  __syncthreads();
  if (t < 8) R[q * 8 + t] = rred[0][t] + rred[1][t] + rred[2][t] + rred[3][t];
}

// ---- QKV projection GEMM, 128x128 m97-shape tiles ---------------------------
// grid (64, 12): m0 over 8192 x-rows, n0 over 1536 stacked W rows (Wq|Wk|Wv).
// Wave w owns the 64x64 quadrant ((w>>1)*64, (w&1)*64): acc[4][4] 16x16 frags,
// 32 MFMA per K64-iter vs 16 in the old 128x64 shape. Block (0,0) also
// zeroes denom and reduces gsums (hidden behind the other 767 blocks).
__global__ __launch_bounds__(256) void proj_k(
    const u16* __restrict__ xb, const u16* __restrict__ Wb,
    const int* __restrict__ mask, const float* __restrict__ R,
    float* __restrict__ sums,
    u16* __restrict__ Qb, u16* __restrict__ Kb, u16* __restrict__ Vtb) {
  const int m0 = blockIdx.x * 128;
  const int n0 = blockIdx.y * 128;
  __shared__ __align__(16) u16 As[128 * 64];
  __shared__ __align__(16) u16 Bs[128 * 64];
  __shared__ float rr[4][8];
  const int t = threadIdx.x, w = t >> 6, lane = t & 63;
  const int l15 = lane & 15, quad = lane >> 4;
  const int mq = (w >> 1) * 64, nq = (w & 1) * 64;

  if (blockIdx.x == 0 && blockIdx.y == 0) {   // gsums + denom-zero (hidden)
    float a8[8] = {0,0,0,0,0,0,0,0};
    for (int q = t; q < 1024; q += 256)
#pragma unroll
      for (int b = 0; b < 8; ++b)
        if (mask[b * 1024 + q]) a8[b] += R[q * 8 + b];
#pragma unroll
    for (int b = 0; b < 8; ++b) {
#pragma unroll
      for (int off = 32; off > 0; off >>= 1) a8[b] += __shfl_down(a8[b], off);
    }
    if (lane == 0)
#pragma unroll
      for (int b = 0; b < 8; ++b) rr[w][b] = a8[b];
    __syncthreads();
    if (t < 8) {
      sums[t] = 0.0f;
      sums[8 + t] = rr[0][t] + rr[1][t] + rr[2][t] + rr[3][t];
    }
  }

  const ffrag fz = {0.f, 0.f, 0.f, 0.f};
  ffrag acc[4][4];
#pragma unroll
  for (int i = 0; i < 4; ++i)
#pragma unroll
    for (int j = 0; j < 4; ++j) acc[i][j] = fz;

  for (int kk = 0; kk < 512; kk += 64) {
    __syncthreads();
#pragma unroll
    for (int j = 0; j < 4; ++j) {
      const int c = w * 256 + j * 64 + lane;
      const int row = c >> 3, ck = (c & 7) ^ (row & 7);
      gll16(xb + (size_t)(m0 + row) * 512 + kk + ck * 8,
            &As[(size_t)(w * 256 + j * 64) * 8]);
    }
#pragma unroll
    for (int j = 0; j < 4; ++j) {
      const int c = w * 256 + j * 64 + lane;
      const int row = c >> 3, ck = (c & 7) ^ (row & 7);
      gll16(Wb + (size_t)(n0 + row) * 512 + kk + ck * 8,
            &Bs[(size_t)(w * 256 + j * 64) * 8]);
    }
    __syncthreads();
#pragma unroll
    for (int s = 0; s < 2; ++s) {
      bfrag av[4], bv[4];
#pragma unroll
      for (int i = 0; i < 4; ++i) {
        const int ar = mq + i * 16 + l15;
        av[i] = *(const bfrag*)&As[ar * 64 + (((quad + 4 * s) ^ (ar & 7)) << 3)];
        const int br = nq + i * 16 + l15;
        bv[i] = *(const bfrag*)&Bs[br * 64 + (((quad + 4 * s) ^ (br & 7)) << 3)];
      }
#pragma unroll
      for (int i = 0; i < 4; ++i)
#pragma unroll
        for (int j = 0; j < 4; ++j)
          acc[i][j] = __builtin_amdgcn_mfma_f32_16x16x32_bf16(av[i], bv[j], acc[i][j], 0, 0, 0);
    }
  }
  const int z = n0 >> 9;          // which of Wq/Wk/Wv (128 | 512)
  const int c0 = n0 & 511;
#pragma unroll
  for (int i = 0; i < 4; ++i) {
    const int mbase = m0 + mq + i * 16 + quad * 4;
    const int b = mbase >> 10, l0 = mbase & 1023;
#pragma unroll
    for (int j = 0; j < 4; ++j) {
      const int nc = c0 + nq + j * 16 + l15;
      const int h = nc >> 6, d = nc & 63;
      if (z == 0) {
        u16* dst = Qb + ((size_t)(b * 8 + h) * 1024 + l0) * 64 + d;
#pragma unroll
        for (int r = 0; r < 4; ++r) dst[(size_t)r * 64] = f2b(acc[i][j][r]);
      } else if (z == 1) {
        u16* dst = Kb + ((size_t)(b * 8 + h) * 1024 + l0) * 64 + d;
#pragma unroll
        for (int r = 0; r < 4; ++r) dst[(size_t)r * 64] = f2b(acc[i][j][r]);
      } else {
        vshort4 vs;
#pragma unroll
        for (int r = 0; r < 4; ++r)
          vs[r] = (short)(mask[b * 1024 + l0 + r] ? f2b(acc[i][j][r]) : (u16)0);
        *(vshort4*)(Vtb + ((size_t)(b * 8 + h) * 64 + d) * 1024 + l0) = vs;
      }
    }
  }
}

// ---- fused tanh-attention + global-mix GEMM, 32x32 MFMA (R9 exact) ----------
// S-phase: wave (qsb=w>>1, msb=w&1) computes its 32k x 32q block of S^T,
// nonlinearity -> Es. PV (after barrier): wave (qpb=w&1, dpb=w>>1) computes a
// DISTINCT 32q x 32d quadrant of accE/accG (no redundancy); dacc on dpb==0.
__global__ __launch_bounds__(256) void attn_k(
    const u16* __restrict__ Qb, const u16* __restrict__ Kb,
    const u16* __restrict__ Vtb, const u16* __restrict__ actb,
    const int* __restrict__ mask,
    u16* __restrict__ AEb, u16* __restrict__ AGb, float* __restrict__ denom) {
  const int qt = blockIdx.x;
  const int bh = blockIdx.y;
  const int b = bh >> 3, h = bh & 7;
  __shared__ __align__(16) u16 Ks[64 * 64];    // 8 KB [k][d]
  __shared__ __align__(16) u16 Vs[64 * 64];    // 8 KB [d][k]
  __shared__ __align__(16) u16 Acts[64 * 64];  // 8 KB [q][k]
  __shared__ __align__(16) u16 Es[64 * 64];    // 8 KB [q][k]
  __shared__ __align__(16) u16 Ms[1024];       // 2 KB bf16 mask
  __shared__ float red4[4];
  const int t = threadIdx.x, w = t >> 6, lane = t & 63;
  const int l31 = lane & 31, hi = lane >> 5;
  const int qsb = w >> 1, msb = w & 1;   // S-phase: q-block, k(m)-block
  const int qpb = w & 1, dpb = w >> 1;   // PV-phase: q-block, d-block (distinct!)

  const u16* Kg = Kb + (size_t)bh * 65536;
  const u16* Vg = Vtb + (size_t)bh * 65536;
  const u16* Ag = actb + (size_t)(qt * 64) * 1024;

  const u16* Qrow = Qb + ((size_t)bh * 1024 + qt * 64 + qsb * 32 + l31) * 64;
  bfrag qf[4];
#pragma unroll
  for (int ko = 0; ko < 4; ++ko) qf[ko] = *(const bfrag*)(Qrow + ko * 16 + hi * 8);

  {
    int4 mi = *(const int4*)(mask + b * 1024 + t * 4);
    vshort4 mv;
    mv[0] = mi.x ? (short)0x3F80 : (short)0; mv[1] = mi.y ? (short)0x3F80 : (short)0;
    mv[2] = mi.z ? (short)0x3F80 : (short)0; mv[3] = mi.w ? (short)0x3F80 : (short)0;
    *(vshort4*)&Ms[t * 4] = mv;
  }

  auto stageK = [&](int kt) {
#pragma unroll
    for (int j = 0; j < 2; ++j) {
      const int c = w * 128 + j * 64 + lane;
      const int row = c >> 3, ck = (c & 7) ^ SWK(row);
      gll16(Kg + (size_t)(kt * 64 + row) * 64 + ck * 8,
            &Ks[(size_t)(w * 128 + j * 64) * 8]);
    }
  };
  auto stageV = [&](int kt) {
#pragma unroll
    for (int j = 0; j < 2; ++j) {
      const int c = w * 128 + j * 64 + lane;
      const int row = c >> 3, ck = (c & 7) ^ SWK(row);
      gll16(Vg + (size_t)row * 1024 + kt * 64 + ck * 8,
            &Vs[(size_t)(w * 128 + j * 64) * 8]);
    }
  };
  auto stageA = [&](int kt) {
#pragma unroll
    for (int j = 0; j < 2; ++j) {
      const int c = w * 128 + j * 64 + lane;
      const int row = c >> 3, ck = (c & 7) ^ SWK(row);
      gll16(Ag + (size_t)row * 1024 + kt * 64 + ck * 8,
            &Acts[(size_t)(w * 128 + j * 64) * 8]);
    }
  };

  stageK(0); stageV(0); stageA(0);
  __syncthreads();

  ffrag16 accE, accG, dacc;
#pragma unroll
  for (int i = 0; i < 16; ++i) { accE[i] = 0.f; accG[i] = 0.f; dacc[i] = 0.f; }

  for (int kt = 0; kt < 16; ++kt) {
    // ---- S-phase: S^T block (m = wave's 32-k block, n = its 32-q block) ----
    ffrag16 st;
#pragma unroll
    for (int i = 0; i < 16; ++i) st[i] = 0.f;
    const int krow = msb * 32 + l31;
    const int kk7 = SWK(krow);
#pragma unroll
    for (int ko = 0; ko < 4; ++ko) {
      bfrag ak = *(const bfrag*)&Ks[krow * 64 + (((ko * 2 + hi) ^ kk7) << 3)];
      st = __builtin_amdgcn_mfma_f32_32x32x16_bf16(ak, qf[ko], st, 0, 0, 0);
    }
    // ---- nonlinearity -> Es (lane = q col; reg r -> k-local) ----
    const int qrow = qsb * 32 + l31;
    const int qk7 = SWK(qrow);
#pragma unroll
    for (int g = 0; g < 4; ++g) {
      float ee[4];
#pragma unroll
      for (int r = 0; r < 4; ++r) {
        const float tt = EXP2F(st[4 * g + r] * 0.360673760222f);
        ee[r] = EXP2F(RCPF(tt + 1.0f) * -2.88539008178f);
      }
      const int k0 = msb * 32 + g * 8 + hi * 4;
      *(uint2*)&Es[qrow * 64 + (((k0 >> 3) ^ qk7) << 3) + (k0 & 7)] =
          make_uint2(pk2(ee[0], ee[1]), pk2(ee[2], ee[3]));
    }
    __syncthreads();                   // Es visible; Ks reads done blockwide
    if (kt < 15) stageK(kt + 1);       // drains at next barrier

    // ---- PV: distinct quadrant per wave ----
    const int erow = qpb * 32 + l31;
    const int ek7 = SWK(erow);
    const int vrow = dpb * 32 + l31;
    const int vk7 = SWK(vrow);
#pragma unroll
    for (int ko = 0; ko < 4; ++ko) {
      const int co = ko * 2 + hi;
      bfrag ea = *(const bfrag*)&Es[erow * 64 + ((co ^ ek7) << 3)];
      bfrag aa = *(const bfrag*)&Acts[erow * 64 + ((co ^ ek7) << 3)];
      bfrag bv = *(const bfrag*)&Vs[vrow * 64 + ((co ^ vk7) << 3)];
      accE = __builtin_amdgcn_mfma_f32_32x32x16_bf16(ea, bv, accE, 0, 0, 0);
      accG = __builtin_amdgcn_mfma_f32_32x32x16_bf16(aa, bv, accG, 0, 0, 0);
      if (dpb == 0) {
        bfrag bm = *(const bfrag*)&Ms[kt * 64 + ko * 16 + hi * 8];
        dacc = __builtin_amdgcn_mfma_f32_32x32x16_bf16(ea, bm, dacc, 0, 0, 0);
      }
    }
    __syncthreads();                   // Vs/Acts/Es reads done
    if (kt < 15) { stageV(kt + 1); stageA(kt + 1); }
  }

  // ---- epilogue: wave stores its (qpb, dpb) quadrant of AE/AG (bf16) ----
  const size_t obase = ((size_t)(b * 1024 + qt * 64 + qpb * 32)) * 512
                       + h * 64 + dpb * 32 + l31;
#pragma unroll
  for (int r = 0; r < 16; ++r) {
    const int qloc = (r & 3) + 8 * (r >> 2) + 4 * hi;
    AEb[obase + (size_t)qloc * 512] = f2b(accE[r]);
    AGb[obase + (size_t)qloc * 512] = f2b(accG[r]);
  }
  // ---- denominator: dacc cols identical; dpb==0 waves hold q-blocks 0,1 ----
  float dsumv = 0.0f;
  if (l31 == 0 && dpb == 0) {
    const int qb0 = b * 1024 + qt * 64 + qpb * 32 + 4 * hi;
#pragma unroll
    for (int r = 0; r < 16; ++r) {
      const int q = qb0 + (r & 3) + 8 * (r >> 2);
      dsumv += mask[q] ? dacc[r] : 0.0f;
    }
    red4[qpb * 2 + hi] = dsumv;
  }
  __syncthreads();
  if (t == 0) atomicAdd(denom + b, red4[0] + red4[1] + red4[2] + red4[3]);
}

// ---- out = (mq*(c1*AEb + c2*AGb)) @ Wo^T, 128x128 tiles ---------------------
__global__ __launch_bounds__(256) void o_proj_k(
    const u16* __restrict__ AEb, const u16* __restrict__ AGb,
    const int* __restrict__ mask, const float* __restrict__ sums,
    const u16* __restrict__ Wb, float* __restrict__ out) {
  const int m0 = blockIdx.x * 128;
  const int n0 = blockIdx.y * 128;
  const int b = m0 >> 10;
  const float c1 = 0.5f / fmaxf(sums[b], TINYF);
  const float c2 = 0.5f / fmaxf(sums[8 + b], TINYF);
  __shared__ __align__(16) u16 As[128 * 64];
  __shared__ __align__(16) u16 Bs[128 * 64];
  const int t = threadIdx.x, w = t >> 6, lane = t & 63;
  const int l15 = lane & 15, quad = lane >> 4;
  const int mq = (w >> 1) * 64, nq = (w & 1) * 64;
  int rowi[4]; float c1r[4], c2r[4];
#pragma unroll
  for (int i = 0; i < 4; ++i) {
    const int c = t + i * 256;
    rowi[i] = c >> 3;
    const int mqv = mask[b * 1024 + ((m0 + rowi[i]) & 1023)];
    c1r[i] = mqv ? c1 : 0.0f;
    c2r[i] = mqv ? c2 : 0.0f;
  }
  const ffrag fz = {0.f, 0.f, 0.f, 0.f};
  ffrag acc[4][4];
#pragma unroll
  for (int i = 0; i < 4; ++i)
#pragma unroll
    for (int j = 0; j < 4; ++j) acc[i][j] = fz;

  for (int kk = 0; kk < 512; kk += 64) {
    __syncthreads();
#pragma unroll
    for (int i = 0; i < 4; ++i) {
      const int c = t + i * 256;
      const int row = rowi[i], ck = c & 7;
      const size_t gofs = (size_t)(m0 + row) * 512 + kk + ck * 8;
      uint4 ua = *(const uint4*)(AEb + gofs);
      uint4 ug = *(const uint4*)(AGb + gofs);
      const float a1 = c1r[i], a2 = c2r[i];
      uint4 res;
      res.x = pk2(a1 * blo(ua.x) + a2 * blo(ug.x), a1 * bhi(ua.x) + a2 * bhi(ug.x));
      res.y = pk2(a1 * blo(ua.y) + a2 * blo(ug.y), a1 * bhi(ua.y) + a2 * bhi(ug.y));
      res.z = pk2(a1 * blo(ua.z) + a2 * blo(ug.z), a1 * bhi(ua.z) + a2 * bhi(ug.z));
      res.w = pk2(a1 * blo(ua.w) + a2 * blo(ug.w), a1 * bhi(ua.w) + a2 * bhi(ug.w));
      *(uint4*)&As[row * 64 + ((ck ^ (row & 7)) << 3)] = res;
    }
#pragma unroll
    for (int j = 0; j < 4; ++j) {
      const int c = w * 256 + j * 64 + lane;
      const int row = c >> 3, ck = (c & 7) ^ (row & 7);
      gll16(Wb + (size_t)(1536 + n0 + row) * 512 + kk + ck * 8,
            &Bs[(size_t)(w * 256 + j * 64) * 8]);
    }
    __syncthreads();
#pragma unroll
    for (int s = 0; s < 2; ++s) {
      bfrag av[4], bv[4];
#pragma unroll
      for (int i = 0; i < 4; ++i) {
        const int ar = mq + i * 16 + l15;
        av[i] = *(const bfrag*)&As[ar * 64 + (((quad + 4 * s) ^ (ar & 7)) << 3)];
        const int br = nq + i * 16 + l15;
        bv[i] = *(const bfrag*)&Bs[br * 64 + (((quad + 4 * s) ^ (br & 7)) << 3)];
      }
#pragma unroll
      for (int i = 0; i < 4; ++i)
#pragma unroll
        for (int j = 0; j < 4; ++j)
          acc[i][j] = __builtin_amdgcn_mfma_f32_16x16x32_bf16(av[i], bv[j], acc[i][j], 0, 0, 0);
    }
  }
#pragma unroll
  for (int i = 0; i < 4; ++i) {
    const int mbase = m0 + mq + i * 16 + quad * 4;
#pragma unroll
    for (int j = 0; j < 4; ++j) {
      const int n = n0 + nq + j * 16 + l15;
#pragma unroll
      for (int r = 0; r < 4; ++r)
        out[(size_t)(mbase + r) * 512 + n] = acc[i][j][r];
    }
  }
}

extern "C" void kernel_launch(void* const* d_in, const int* in_sizes, int n_in,
                              void* d_out, int out_size, void* d_ws, size_t ws_size,
                              hipStream_t stream) {
  const float* x  = (const float*)d_in[0];
  const int* mask = (const int*)d_in[1];
  const float* Wq = (const float*)d_in[2];
  const float* Wk = (const float*)d_in[3];
  const float* Wv = (const float*)d_in[4];
  const float* Wo = (const float*)d_in[5];
  const float* G  = (const float*)d_in[6];
  float* out = (float*)d_out;

  u16* xb   = (u16*)d_ws;                    // 8192*512
  u16* Wb   = xb + (size_t)8192 * 512;       // 2048*512
  u16* Qb   = Wb + (size_t)2048 * 512;       // QSZ
  u16* Kb   = Qb + QSZ;
  u16* Vtb  = Kb + QSZ;
  u16* actb = Vtb + QSZ;                     // 1024*1024
  u16* AEb  = actb + (size_t)1024 * 1024;    // BLE
  u16* AGb  = AEb + BLE;                     // BLE
  float* R  = (float*)(AGb + BLE);           // 1024*8
  float* SUMS = R + 8192;                    // denom[8], gsums[8]

  prep_softmax_k<<<3584, 256, 0, stream>>>(x, Wq, Wk, Wv, Wo, G, mask, xb, Wb, actb, R);
  proj_k<<<dim3(64, 12), 256, 0, stream>>>(xb, Wb, mask, R, SUMS, Qb, Kb, Vtb);
  attn_k<<<dim3(16, 64), 256, 0, stream>>>(Qb, Kb, Vtb, actb, mask, AEb, AGb, SUMS);
  o_proj_k<<<dim3(64, 4), 256, 0, stream>>>(AEb, AGb, mask, SUMS, Wb, out);
}